// Round 1
// baseline (36256.338 us; speedup 1.0000x reference)
//
#include <hip/hip_runtime.h>
#include <cstdint>

// Decoder: S=128, B=32, H=E=512, L=2, V=32000, heads=8, dk=64, T=128 steps.
// Strategy (round 1, all-fp32 for argmax fidelity):
//  - One-time per launch: transpose all weights to K-major in ws; precompute
//    k/v projections of hs; zero out[:,0,:].
//  - Per step (x127): LSTM l0 (fused gates+activation), LSTM l1, fused
//    q+attention+Wo, logits (K-split x2), finalize (+argmax block keys).
//  - Token flows via per-block argmax keys; next step's LSTM l0 reduces them.

#define B_ 32
#define H_ 512
#define V_ 32000
#define S_ 128
#define NH_ 8
#define DK_ 64

// ---- workspace float offsets ----
static const size_t o_WoutT = 0;                                  // [512][32000]
static const size_t o_Wcat  = o_WoutT + (size_t)512 * 32000;      // [2][1024][2048] gate-interleaved
static const size_t o_Wqt   = o_Wcat  + (size_t)2 * 1024 * 2048;  // [512][512]
static const size_t o_Wot   = o_Wqt   + (size_t)512 * 512;        // [512][512]
static const size_t o_WkvT  = o_Wot   + (size_t)512 * 512;        // [512][1024] (Wk|Wv)
static const size_t o_kT    = o_WkvT  + (size_t)512 * 1024;       // [32][8][64][128]
static const size_t o_vT    = o_kT    + (size_t)B_ * NH_ * DK_ * S_; // [32][8][128][64]
static const size_t o_h     = o_vT    + (size_t)B_ * NH_ * S_ * DK_; // [2pp][2l][32][512]
static const size_t o_c     = o_h     + (size_t)2 * 2 * B_ * H_;
static const size_t o_attnT = o_c     + (size_t)2 * 2 * B_ * H_;  // [512][32]
static const size_t o_part  = o_attnT + (size_t)H_ * B_;          // [2][32][32000]
static const size_t o_keys  = o_part  + (size_t)2 * B_ * V_;      // u64[125][32]

// ---------------- prep kernels ----------------

// in[M][K] row-major -> out[k*ldout + m]
__global__ void transpose_k(const float* __restrict__ in, float* __restrict__ out,
                            int M, int K, int ldout) {
    __shared__ float tile[32][33];
    int m0 = blockIdx.x * 32, k0 = blockIdx.y * 32;
    int tx = threadIdx.x & 31, ty = threadIdx.x >> 5;  // ty: 0..7
    #pragma unroll
    for (int r = 0; r < 32; r += 8) {
        int m = m0 + ty + r, k = k0 + tx;
        tile[ty + r][tx] = in[(size_t)m * K + k];
    }
    __syncthreads();
    #pragma unroll
    for (int r = 0; r < 32; r += 8) {
        int k = k0 + ty + r, m = m0 + tx;
        out[(size_t)k * ldout + m] = tile[tx][ty + r];
    }
}

// Build Wcat[l][k][n], n = j*4+g, k<512 from W_ih[l][g*512+j][k], else W_hh.
__global__ void lstm_prep(const float* __restrict__ Wih, const float* __restrict__ Whh,
                          float* __restrict__ Wcat) {
    int l = blockIdx.z, jt = blockIdx.x, kt = blockIdx.y;
    __shared__ float tl[4][32][33];
    int tid = threadIdx.x;
    #pragma unroll
    for (int rep = 0; rep < 16; ++rep) {
        int idx = rep * 256 + tid;
        int rl = idx >> 5, kk = idx & 31;
        int g = rl >> 5, j = rl & 31;
        int k = kt * 32 + kk;
        int row = g * 512 + jt * 32 + j;
        const float* src = (k < 512)
            ? (Wih + (size_t)l * 2048 * 512 + (size_t)row * 512 + k)
            : (Whh + (size_t)l * 2048 * 512 + (size_t)row * 512 + (k - 512));
        tl[g][j][kk] = *src;
    }
    __syncthreads();
    #pragma unroll
    for (int rep = 0; rep < 16; ++rep) {
        int idx = rep * 256 + tid;
        int kk = idx >> 7, nn = idx & 127;
        int j = nn >> 2, g = nn & 3;
        Wcat[(size_t)l * 1024 * 2048 + (size_t)(kt * 32 + kk) * 2048 + jt * 128 + nn] =
            tl[g][j][kk];
    }
}

// zero out[:,0,:]
__global__ void zero_kernel(float* __restrict__ out) {
    size_t idx = (size_t)blockIdx.x * 256 + threadIdx.x;
    size_t total = (size_t)B_ * V_;
    for (size_t i = idx; i < total; i += (size_t)gridDim.x * 256) {
        size_t b = i / V_, v = i % V_;
        out[b * 128 * V_ + v] = 0.f;
    }
}

// k/v precompute: per (s=g, n in [0,1024)): dot over K=512 of hs rows, write permuted.
__global__ __launch_bounds__(256) void kv_kernel(
    const float* __restrict__ hs, const float* __restrict__ WkvT,
    const float* __restrict__ bk, const float* __restrict__ bv,
    float* __restrict__ kT, float* __restrict__ vT) {
    int n = blockIdx.x * 256 + threadIdx.x;  // 0..1023
    int g = blockIdx.y;                      // s: 0..127
    float bias = (n < 512) ? bk[n] : bv[n - 512];
    float acc[32];
    #pragma unroll
    for (int b = 0; b < 32; ++b) acc[b] = bias;
    const float* xbase = hs + (size_t)g * 32 * 512;
    for (int k = 0; k < 512; k += 4) {
        float w0 = WkvT[(size_t)(k + 0) * 1024 + n];
        float w1 = WkvT[(size_t)(k + 1) * 1024 + n];
        float w2 = WkvT[(size_t)(k + 2) * 1024 + n];
        float w3 = WkvT[(size_t)(k + 3) * 1024 + n];
        #pragma unroll
        for (int b = 0; b < 32; ++b) {
            const float* xr = xbase + (size_t)b * 512 + k;  // uniform -> s_load
            acc[b] += xr[0] * w0 + xr[1] * w1 + xr[2] * w2 + xr[3] * w3;
        }
    }
    if (n < 512) {
        int h = n >> 6, d = n & 63;
        #pragma unroll
        for (int b = 0; b < 32; ++b)
            kT[(((size_t)b * NH_ + h) * DK_ + d) * S_ + g] = acc[b];
    } else {
        int n2 = n - 512;
        int h = n2 >> 6, d = n2 & 63;
        #pragma unroll
        for (int b = 0; b < 32; ++b)
            vT[(((size_t)b * NH_ + h) * S_ + g) * DK_ + d] = acc[b];
    }
}

// ---------------- per-step kernels ----------------

// LSTM layer: fused gates + activation. grid (8 nblk, 8 mblk) x 256 thr.
__global__ __launch_bounds__(256) void lstm_kernel(
    int l, int t,
    const float* __restrict__ emb, const float* __restrict__ Wcat,
    const float* __restrict__ b_ih, const float* __restrict__ b_hh,
    const unsigned long long* __restrict__ bkeys,
    float* __restrict__ hbuf, float* __restrict__ cbuf) {
    const int rb = (t - 1) & 1, wb = t & 1;
    const int n = blockIdx.x * 256 + threadIdx.x;  // gate col 0..2047
    const int mb = blockIdx.y * 4;
    const int j = n >> 2, g = n & 3;
    float bias = b_ih[l * 2048 + g * 512 + j] + b_hh[l * 2048 + g * 512 + j];
    float acc[4];
    #pragma unroll
    for (int i = 0; i < 4; ++i) acc[i] = bias;

    const float* xrow[4];
    #pragma unroll
    for (int i = 0; i < 4; ++i) {
        int m = mb + i;
        if (l == 0) {
            int tok = 0;  // SOS
            if (t > 1) {
                unsigned long long best = 0ull;
                for (int q = 0; q < 125; ++q) {
                    unsigned long long kk = bkeys[q * 32 + m];
                    best = kk > best ? kk : best;
                }
                tok = (int)(0xFFFFFFFFu - (unsigned)(best & 0xFFFFFFFFull));
            }
            xrow[i] = emb + (size_t)tok * 512;
        } else {
            xrow[i] = hbuf + ((size_t)wb * 2 + 0) * B_ * H_ + (size_t)m * 512;  // new h0
        }
    }
    const float* hrow[4];
    #pragma unroll
    for (int i = 0; i < 4; ++i)
        hrow[i] = hbuf + ((size_t)rb * 2 + l) * B_ * H_ + (size_t)(mb + i) * 512;

    const float* Wl = Wcat + (size_t)l * 1024 * 2048;
    for (int k = 0; k < 512; k += 4) {
        float w0 = Wl[(size_t)(k + 0) * 2048 + n];
        float w1 = Wl[(size_t)(k + 1) * 2048 + n];
        float w2 = Wl[(size_t)(k + 2) * 2048 + n];
        float w3 = Wl[(size_t)(k + 3) * 2048 + n];
        #pragma unroll
        for (int i = 0; i < 4; ++i) {
            const float* xr = xrow[i] + k;  // uniform -> s_load
            acc[i] += xr[0] * w0 + xr[1] * w1 + xr[2] * w2 + xr[3] * w3;
        }
    }
    for (int k = 0; k < 512; k += 4) {
        float w0 = Wl[(size_t)(512 + k + 0) * 2048 + n];
        float w1 = Wl[(size_t)(512 + k + 1) * 2048 + n];
        float w2 = Wl[(size_t)(512 + k + 2) * 2048 + n];
        float w3 = Wl[(size_t)(512 + k + 3) * 2048 + n];
        #pragma unroll
        for (int i = 0; i < 4; ++i) {
            const float* hr = hrow[i] + k;  // uniform -> s_load
            acc[i] += hr[0] * w0 + hr[1] * w1 + hr[2] * w2 + hr[3] * w3;
        }
    }

    __shared__ float G[4][256];
    #pragma unroll
    for (int i = 0; i < 4; ++i) G[i][threadIdx.x] = acc[i];
    __syncthreads();
    int mi = threadIdx.x >> 6, jl = threadIdx.x & 63;
    float gi = G[mi][jl * 4 + 0];
    float gf = G[mi][jl * 4 + 1];
    float gg = G[mi][jl * 4 + 2];
    float go = G[mi][jl * 4 + 3];
    int m = mb + mi;
    int jg = blockIdx.x * 64 + jl;
    size_t ridx = ((size_t)rb * 2 + l) * B_ * H_ + (size_t)m * 512 + jg;
    size_t widx = ((size_t)wb * 2 + l) * B_ * H_ + (size_t)m * 512 + jg;
    float cold = cbuf[ridx];
    float si = 1.f / (1.f + expf(-gi));
    float sf = 1.f / (1.f + expf(-gf));
    float so = 1.f / (1.f + expf(-go));
    float cn = sf * cold + si * tanhf(gg);
    cbuf[widx] = cn;
    hbuf[widx] = so * tanhf(cn);
}

// Fused q-projection + attention + Wo. grid 32 (b) x 512 thr (8 waves = heads).
__global__ __launch_bounds__(512) void attn_kernel(
    int t, const float* __restrict__ hbuf,
    const float* __restrict__ Wqt, const float* __restrict__ bq,
    const float* __restrict__ kT, const float* __restrict__ vT,
    const float* __restrict__ Wot, const float* __restrict__ bo,
    float* __restrict__ attnT) {
    const int wb = t & 1;
    const int b = blockIdx.x;
    const int lane = threadIdx.x & 63, h = threadIdx.x >> 6;
    const float* hrow = hbuf + ((size_t)wb * 2 + 1) * B_ * H_ + (size_t)b * 512;
    int n = h * 64 + lane;
    float q = bq[n];
    for (int k = 0; k < 512; k += 4) {
        float h0 = hrow[k], h1 = hrow[k + 1], h2 = hrow[k + 2], h3 = hrow[k + 3];
        q += h0 * Wqt[(size_t)(k + 0) * 512 + n] + h1 * Wqt[(size_t)(k + 1) * 512 + n] +
             h2 * Wqt[(size_t)(k + 2) * 512 + n] + h3 * Wqt[(size_t)(k + 3) * 512 + n];
    }
    // scores (lane holds s = 2*lane, 2*lane+1)
    const float* kTb = kT + ((size_t)b * NH_ + h) * DK_ * S_;
    float s0 = 0.f, s1 = 0.f;
    for (int d = 0; d < 64; ++d) {
        float qd = __shfl(q, d, 64);
        const float* kr = kTb + (size_t)d * S_ + 2 * lane;
        s0 += qd * kr[0];
        s1 += qd * kr[1];
    }
    s0 *= 0.125f;
    s1 *= 0.125f;
    float mx = fmaxf(s0, s1);
    #pragma unroll
    for (int o = 32; o; o >>= 1) mx = fmaxf(mx, __shfl_xor(mx, o, 64));
    float e0 = expf(s0 - mx), e1 = expf(s1 - mx);
    float sum = e0 + e1;
    #pragma unroll
    for (int o = 32; o; o >>= 1) sum += __shfl_xor(sum, o, 64);
    float inv = 1.f / sum;
    float p0 = e0 * inv, p1 = e1 * inv;
    // attn accumulate (lane = d)
    const float* vTb = vT + ((size_t)b * NH_ + h) * S_ * DK_;
    float a = 0.f;
    for (int s = 0; s < 128; s += 2) {
        float pa = __shfl(p0, s >> 1, 64);
        float pb = __shfl(p1, s >> 1, 64);
        a += pa * vTb[(size_t)s * DK_ + lane] + pb * vTb[(size_t)(s + 1) * DK_ + lane];
    }
    __shared__ float att[512];
    att[n] = a;
    __syncthreads();
    // Wo: thread -> output col
    int nn = threadIdx.x;
    float o_ = bo[nn];
    for (int k = 0; k < 512; k += 4) {
        float a0 = att[k], a1 = att[k + 1], a2 = att[k + 2], a3 = att[k + 3];
        o_ += a0 * Wot[(size_t)(k + 0) * 512 + nn] + a1 * Wot[(size_t)(k + 1) * 512 + nn] +
              a2 * Wot[(size_t)(k + 2) * 512 + nn] + a3 * Wot[(size_t)(k + 3) * 512 + nn];
    }
    attnT[(size_t)nn * 32 + b] = o_;  // transposed for scalar loads downstream
}

// logits partials: grid (125 nblk, 2 kblk) x 256 thr; 32 batch accumulators/thread.
__global__ __launch_bounds__(256) void logits_kernel(
    const float* __restrict__ WoutT, const float* __restrict__ attnT,
    float* __restrict__ part) {
    int n = blockIdx.x * 256 + threadIdx.x;
    int kb = blockIdx.y;
    float acc[32];
    #pragma unroll
    for (int m = 0; m < 32; ++m) acc[m] = 0.f;
    int k0 = kb * 256;
    for (int k = k0; k < k0 + 256; k += 2) {
        const float* ar = attnT + (size_t)k * 32;  // uniform -> s_load
        float w0 = WoutT[(size_t)k * V_ + n];
        float w1 = WoutT[(size_t)(k + 1) * V_ + n];
        #pragma unroll
        for (int m = 0; m < 32; ++m) acc[m] += ar[m] * w0 + ar[32 + m] * w1;
    }
    float* pp = part + (size_t)kb * 32 * V_;
    #pragma unroll
    for (int m = 0; m < 32; ++m) pp[(size_t)m * V_ + n] = acc[m];
}

// finalize: sum partials + bias, write out[:,t,:], per-block argmax keys.
__global__ __launch_bounds__(256) void final_kernel(
    int t, const float* __restrict__ part, const float* __restrict__ b_out,
    float* __restrict__ out, unsigned long long* __restrict__ bkeys) {
    int n = blockIdx.x * 256 + threadIdx.x;
    float bias = b_out[n];
    __shared__ unsigned long long red[4][32];
    const float* p0 = part;
    const float* p1 = part + (size_t)32 * V_;
    for (int m = 0; m < 32; ++m) {
        float v = p0[(size_t)m * V_ + n] + p1[(size_t)m * V_ + n] + bias;
        out[((size_t)m * 128 + t) * V_ + n] = v;
        unsigned u = __float_as_uint(v);
        u = (u & 0x80000000u) ? ~u : (u | 0x80000000u);
        unsigned long long key =
            ((unsigned long long)u << 32) | (unsigned long long)(0xFFFFFFFFu - (unsigned)n);
        #pragma unroll
        for (int o = 32; o; o >>= 1) {
            unsigned long long other = __shfl_xor(key, o, 64);
            key = other > key ? other : key;
        }
        if ((threadIdx.x & 63) == 0) red[threadIdx.x >> 6][m] = key;
    }
    __syncthreads();
    if (threadIdx.x < 32) {
        int m = threadIdx.x;
        unsigned long long k0 = red[0][m], k1 = red[1][m];
        unsigned long long k2 = red[2][m], k3 = red[3][m];
        unsigned long long kk = k0 > k1 ? k0 : k1;
        unsigned long long k23 = k2 > k3 ? k2 : k3;
        kk = kk > k23 ? kk : k23;
        bkeys[blockIdx.x * 32 + m] = kk;
    }
}

// ---------------- launcher ----------------

extern "C" void kernel_launch(void* const* d_in, const int* in_sizes, int n_in,
                              void* d_out, int out_size, void* d_ws, size_t ws_size,
                              hipStream_t stream) {
    const float* hs     = (const float*)d_in[0];
    const float* hidden = (const float*)d_in[1];
    const float* cell   = (const float*)d_in[2];
    const float* emb    = (const float*)d_in[3];
    const float* W_ih   = (const float*)d_in[4];
    const float* W_hh   = (const float*)d_in[5];
    const float* b_ih   = (const float*)d_in[6];
    const float* b_hh   = (const float*)d_in[7];
    const float* Wq     = (const float*)d_in[8];
    const float* bq     = (const float*)d_in[9];
    const float* Wk     = (const float*)d_in[10];
    const float* bk     = (const float*)d_in[11];
    const float* Wv     = (const float*)d_in[12];
    const float* bv     = (const float*)d_in[13];
    const float* Wo     = (const float*)d_in[14];
    const float* bo     = (const float*)d_in[15];
    const float* W_out  = (const float*)d_in[16];
    const float* b_out  = (const float*)d_in[17];
    float* out = (float*)d_out;
    float* ws = (float*)d_ws;

    float* WoutT = ws + o_WoutT;
    float* Wcat  = ws + o_Wcat;
    float* Wqt   = ws + o_Wqt;
    float* Wot   = ws + o_Wot;
    float* WkvT  = ws + o_WkvT;
    float* kT    = ws + o_kT;
    float* vT    = ws + o_vT;
    float* hbuf  = ws + o_h;
    float* cbuf  = ws + o_c;
    float* attnT = ws + o_attnT;
    float* partb = ws + o_part;
    unsigned long long* bkeys = (unsigned long long*)(ws + o_keys);

    // init recurrent state (pp=0 holds both layers contiguously, same layout as inputs)
    hipMemcpyAsync(hbuf, hidden, (size_t)2 * B_ * H_ * sizeof(float),
                   hipMemcpyDeviceToDevice, stream);
    hipMemcpyAsync(cbuf, cell, (size_t)2 * B_ * H_ * sizeof(float),
                   hipMemcpyDeviceToDevice, stream);

    zero_kernel<<<500, 256, 0, stream>>>(out);
    transpose_k<<<dim3(1000, 16), 256, 0, stream>>>(W_out, WoutT, 32000, 512, 32000);
    transpose_k<<<dim3(16, 16), 256, 0, stream>>>(Wq, Wqt, 512, 512, 512);
    transpose_k<<<dim3(16, 16), 256, 0, stream>>>(Wo, Wot, 512, 512, 512);
    transpose_k<<<dim3(16, 16), 256, 0, stream>>>(Wk, WkvT, 512, 512, 1024);
    transpose_k<<<dim3(16, 16), 256, 0, stream>>>(Wv, WkvT + 512, 512, 512, 1024);
    lstm_prep<<<dim3(16, 32, 2), 256, 0, stream>>>(W_ih, W_hh, Wcat);
    kv_kernel<<<dim3(4, 128), 256, 0, stream>>>(hs, WkvT, bk, bv, kT, vT);

    for (int t = 1; t < 128; ++t) {
        lstm_kernel<<<dim3(8, 8), 256, 0, stream>>>(0, t, emb, Wcat, b_ih, b_hh,
                                                    bkeys, hbuf, cbuf);
        lstm_kernel<<<dim3(8, 8), 256, 0, stream>>>(1, t, emb, Wcat, b_ih, b_hh,
                                                    bkeys, hbuf, cbuf);
        attn_kernel<<<32, 512, 0, stream>>>(t, hbuf, Wqt, bq, kT, vT, Wot, bo, attnT);
        logits_kernel<<<dim3(125, 2), 256, 0, stream>>>(WoutT, attnT, partb);
        final_kernel<<<125, 256, 0, stream>>>(t, partb, b_out, out, bkeys);
    }
}